// Round 1
// baseline (6374.846 us; speedup 1.0000x reference)
//
#include <hip/hip_runtime.h>
#include <math.h>

// Problem: 2-layer LSTM (H=512), teacher phase T=1024 steps, then 64 AR steps.
// KEY: only batch row 255 affects the output -> single-sequence LSTM.
// Persistent kernel: weights live in VGPRs (96 floats/thread over 64 WGs x 512 thr),
// h broadcast through global memory, hand-rolled grid barrier per step.

#define G    64      // workgroups
#define NT   512     // threads per wg (8 waves)
#define HD   512     // hidden size
#define TT   1024    // teacher steps
#define PRED 64      // prediction length
#define SCOPE_AGENT __HIP_MEMORY_SCOPE_AGENT

__device__ __forceinline__ float sigf(float x){ return 1.0f/(1.0f+expf(-x)); }

__global__ __launch_bounds__(NT, 2) void lstm2_kernel(
    const float* __restrict__ input,
    const float* __restrict__ Wih1, const float* __restrict__ Whh1,
    const float* __restrict__ bih1, const float* __restrict__ bhh1,
    const float* __restrict__ Wih2, const float* __restrict__ Whh2,
    const float* __restrict__ bih2, const float* __restrict__ bhh2,
    const float* __restrict__ Wlin, const float* __restrict__ blin,
    float* __restrict__ out, float* __restrict__ ws)
{
  __shared__ __align__(16) float hvec[1024];   // [h_a(512) | h_b(512)] staged per tick
  __shared__ __align__(16) float xrow[TT];     // input row 255, loaded once
  __shared__ float part1[64*33];               // L1 partials [seg][row], stride 33 (bank-safe)
  __shared__ float part2[64*33];               // L2 partials
  __shared__ float p1b[8*33];
  __shared__ float p2b[8*33];
  __shared__ float pre1[32];                   // L1 pre-activations (4 gates x 8 units)
  __shared__ float pre2[32];
  __shared__ float xslot;                      // AR feedback scalar o

  unsigned* cnt = (unsigned*)ws;               // grid barrier counter
  unsigned* gen = cnt + 1;                     // grid barrier generation
  float* h1b = ws + 8;                         // h1 double buffer [2][512]
  float* h2b = ws + 8 + 2*HD;                  // h2 double buffer [2][512]

  const int t  = threadIdx.x;
  const int wg = blockIdx.x;
  const int rg = t >> 6;     // row-group 0..7 (== wave id)
  const int sg = t & 63;     // segment (lane)

  // stage input row 255 into LDS (1024 floats, float2 per thread)
  ((float2*)xrow)[t] = ((const float2*)(input + 255*TT))[t];

  // ---- weight preload into registers ----
  // This wg owns hidden units [wg*8, wg*8+8) of each layer: 32 rows/layer
  // (4 gates x 8 units). Local row r = q*8+u -> global row q*512 + wg*8 + u.
  // Thread: 4 rows (rg*4..rg*4+3), L1 seg = 8 floats, L2 seg = 16 floats (of the
  // [Wih2|Whh2] 1024-wide concat row).
  float4 w1[4][2], w2[4][4];
  #pragma unroll
  for (int k=0;k<4;k++){
    const int r = rg*4 + k;
    const int R = (r>>3)*HD + wg*8 + (r&7);
    const float* p = Whh1 + R*HD + sg*8;
    w1[k][0] = *(const float4*)(p);
    w1[k][1] = *(const float4*)(p+4);
    const float* sel = (sg < 32) ? Wih2 : Whh2;   // concat col = sg*16
    const float* q2  = sel + R*HD + (sg&31)*16;
    #pragma unroll
    for (int j=0;j<4;j++) w2[k][j] = *(const float4*)(q2 + j*4);
  }

  // combine-lane preloads: t<8 -> layer1 unit t; t in [8,16) -> layer2 unit t-8
  float bias[4] = {0,0,0,0}, wx[4] = {0,0,0,0};
  float cst = 0.0f;    // persistent cell state (c1 for t<8, c2 for t in [8,16))
  if (t < 8){
    #pragma unroll
    for (int qq=0;qq<4;qq++){
      int R = qq*HD + wg*8 + t;
      bias[qq] = bih1[R] + bhh1[R];
      wx[qq]   = Wih1[R];
    }
  } else if (t < 16){
    #pragma unroll
    for (int qq=0;qq<4;qq++){
      int R = qq*HD + wg*8 + (t-8);
      bias[qq] = bih2[R] + bhh2[R];
    }
  }
  float wl[8] = {0,0,0,0,0,0,0,0};
  if (t < 64){
    #pragma unroll
    for (int j=0;j<8;j++) wl[j] = Wlin[t*8+j];
  }
  const float blin0 = blin[0];

  unsigned genv = 0;

  // ---- grid barrier (sense via monotone generation counter) ----
  auto gridbar = [&](){
    ++genv;
    __syncthreads();                     // drain this wg's h-stores before arrival
    if (t == 0){
      unsigned prev = __hip_atomic_fetch_add(cnt, 1u, __ATOMIC_ACQ_REL, SCOPE_AGENT);
      if (prev == (unsigned)(G-1)){
        __hip_atomic_store(cnt, 0u, __ATOMIC_RELAXED, SCOPE_AGENT);
        __hip_atomic_store(gen, genv, __ATOMIC_RELEASE, SCOPE_AGENT);
      } else {
        while (__hip_atomic_load(gen, __ATOMIC_RELAXED, SCOPE_AGENT) < genv) {}
        __builtin_amdgcn_fence(__ATOMIC_ACQUIRE, "agent");  // invalidate stale L1/L2
      }
    }
    __syncthreads();
  };

  auto stage = [&](const float* h1src, const float* h2src){
    if (t < 256) ((float2*)hvec)[t] = ((const float2*)h1src)[t];
    else         ((float2*)hvec)[t] = ((const float2*)h2src)[t-256];
  };

  auto dotsL1 = [&](){
    const float4 h0  = ((const float4*)hvec)[sg*2];
    const float4 h1_ = ((const float4*)hvec)[sg*2+1];
    #pragma unroll
    for (int k=0;k<4;k++){
      const float4 a = w1[k][0], b = w1[k][1];
      part1[sg*33 + rg*4 + k] =
          a.x*h0.x + a.y*h0.y + a.z*h0.z + a.w*h0.w
        + b.x*h1_.x + b.y*h1_.y + b.z*h1_.z + b.w*h1_.w;
    }
  };

  auto dotsL2 = [&](){
    float4 hc[4];
    #pragma unroll
    for (int j=0;j<4;j++) hc[j] = ((const float4*)hvec)[sg*4 + j];
    #pragma unroll
    for (int k=0;k<4;k++){
      float s = 0.f;
      #pragma unroll
      for (int j=0;j<4;j++){
        const float4 w = w2[k][j];
        s += w.x*hc[j].x + w.y*hc[j].y + w.z*hc[j].z + w.w*hc[j].w;
      }
      part2[sg*33 + rg*4 + k] = s;
    }
  };

  auto reduce2 = [&](bool d1, bool d2){
    const int rr = t & 31;
    const int g8 = (t >> 5) & 7;
    if (t < 256){
      if (d1){
        float s = 0.f;
        #pragma unroll
        for (int i=0;i<8;i++) s += part1[(g8*8+i)*33 + rr];
        p1b[g8*33 + rr] = s;
      }
    } else if (d2){
      float s = 0.f;
      #pragma unroll
      for (int i=0;i<8;i++) s += part2[(g8*8+i)*33 + rr];
      p2b[g8*33 + rr] = s;
    }
    __syncthreads();
    if (t < 32){
      if (d1){
        float s = 0.f;
        #pragma unroll
        for (int g=0;g<8;g++) s += p1b[g*33 + t];
        pre1[t] = s;
      }
    } else if (t < 64){
      if (d2){
        float s = 0.f;
        #pragma unroll
        for (int g=0;g<8;g++) s += p2b[g*33 + (t-32)];
        pre2[t-32] = s;
      }
    }
    __syncthreads();
  };

  auto combine = [&](bool d1, bool d2, float xv, float* h1dst, float* h2dst){
    if (d1 && t < 8){
      float pi = pre1[t]    + xv*wx[0] + bias[0];
      float pf = pre1[8+t]  + xv*wx[1] + bias[1];
      float pg = pre1[16+t] + xv*wx[2] + bias[2];
      float po = pre1[24+t] + xv*wx[3] + bias[3];
      cst = sigf(pf)*cst + sigf(pi)*tanhf(pg);
      h1dst[wg*8 + t] = sigf(po)*tanhf(cst);
    }
    if (d2 && t >= 8 && t < 16){
      const int u = t - 8;
      float pi = pre2[u]    + bias[0];
      float pf = pre2[8+u]  + bias[1];
      float pg = pre2[16+u] + bias[2];
      float po = pre2[24+u] + bias[3];
      cst = sigf(pf)*cst + sigf(pi)*tanhf(pg);
      h2dst[wg*8 + u] = sigf(po)*tanhf(cst);
    }
  };

  // o = Wlin . h2 + blin, from hvec[512..1023]; identical in every wg (deterministic)
  auto computeO = [&](int oi){
    if (t < 64){
      float s = 0.f;
      #pragma unroll
      for (int j=0;j<8;j++) s += wl[j]*hvec[512 + t*8 + j];
      #pragma unroll
      for (int m=1;m<64;m<<=1) s += __shfl_xor(s, m, 64);
      if (t == 0){
        const float o = s + blin0;
        xslot = o;
        if (wg == 0 && oi >= 0) out[oi] = o;
      }
    }
  };

  __syncthreads();   // xrow staged

  // ---- teacher phase: tick tk computes L1 step tk  ||  L2 step tk-1 (1 barrier/tick)
  for (int tk=0; tk<TT; ++tk){
    const bool d2 = (tk >= 1);
    stage(h1b + ((tk+1)&1)*HD, h2b + (tk&1)*HD);   // [h1_{tk-1} | h2_{tk-2}]
    __syncthreads();
    dotsL1();
    if (d2) dotsL2();
    __syncthreads();
    reduce2(true, d2);
    combine(true, d2, xrow[tk], h1b + (tk&1)*HD, h2b + ((tk+1)&1)*HD);
    gridbar();
  }

  // ---- drain: L2 step 1023
  stage(h1b + 1*HD, h2b + 0*HD);                   // [h1_1023 | h2_1022]
  __syncthreads();
  dotsL2();
  __syncthreads();
  reduce2(false, true);
  combine(false, true, 0.f, h1b, h2b + 1*HD);      // h2_1023 -> buf[1]
  gridbar();

  // ---- AR phase: steps s = 1024..1086 (2 barriers/step)
  for (int s=TT; s<TT+PRED-1; ++s){
    // tick B: o_{s-1} (emit out[s-T]) + L1 step s
    stage(h1b + ((s+1)&1)*HD, h2b + ((s+1)&1)*HD); // [h1_{s-1} | h2_{s-1}]
    __syncthreads();
    computeO(s - TT);
    dotsL1();
    __syncthreads();
    reduce2(true, false);
    combine(true, false, xslot, h1b + (s&1)*HD, h2b);
    gridbar();

    // tick A: L2 step s
    stage(h1b + (s&1)*HD, h2b + ((s+1)&1)*HD);     // [h1_s | h2_{s-1}]
    __syncthreads();
    dotsL2();
    __syncthreads();
    reduce2(false, true);
    combine(false, true, 0.f, h1b, h2b + (s&1)*HD);
    gridbar();
  }

  // ---- final output o_1086 (h2_1086 is in buf[0])
  stage(h1b, h2b + 0*HD);
  __syncthreads();
  computeO(PRED-1);
}

extern "C" void kernel_launch(void* const* d_in, const int* in_sizes, int n_in,
                              void* d_out, int out_size, void* d_ws, size_t ws_size,
                              hipStream_t stream) {
  const float* input = (const float*)d_in[0];
  // d_in[1] = pred_len (fixed 64, baked in)
  const float* Wih1 = (const float*)d_in[2];
  const float* Whh1 = (const float*)d_in[3];
  const float* bih1 = (const float*)d_in[4];
  const float* bhh1 = (const float*)d_in[5];
  const float* Wih2 = (const float*)d_in[6];
  const float* Whh2 = (const float*)d_in[7];
  const float* bih2 = (const float*)d_in[8];
  const float* bhh2 = (const float*)d_in[9];
  const float* Wlin = (const float*)d_in[10];
  const float* blin = (const float*)d_in[11];

  // zero barrier state + h double-buffers (ws re-poisoned before every launch)
  hipMemsetAsync(d_ws, 0, (8 + 4*HD) * sizeof(float), stream);

  lstm2_kernel<<<dim3(G), dim3(NT), 0, stream>>>(
      input, Wih1, Whh1, bih1, bhh1, Wih2, Whh2, bih2, bhh2, Wlin, blin,
      (float*)d_out, (float*)d_ws);
}

// Round 2
// 3905.352 us; speedup vs baseline: 1.6323x; 1.6323x over previous
//
#include <hip/hip_runtime.h>
#include <math.h>

// 2-layer LSTM (H=512), T=1024 teacher steps + 64 AR steps; only batch row 255
// reaches the output -> single-sequence LSTM. Weights register-resident across
// 64 persistent WGs. Per-tick all-to-all h exchange via data-carrying
// generation lines (one 256B line per WG per parity slot): producers do 16
// plain stores + 1 release store of gen; consumers (wave 0) poll 64 gens in
// parallel, acquire-fence, read data from the same lines. No RMW atomics.

#define G     64      // workgroups
#define NT    512     // threads/wg
#define HD    512     // hidden
#define TT    1024    // teacher steps
#define PRED  64      // prediction length
#define LINEF 64      // floats per comm line (256 B): d[16] | gen @ word 16
#define SLOTF (G*LINEF)
#define AS    __HIP_MEMORY_SCOPE_AGENT

__device__ __forceinline__ float sigf(float x){ return 1.0f/(1.0f+expf(-x)); }
__device__ __forceinline__ float dot4(float4 a, float4 b){
  return a.x*b.x + a.y*b.y + a.z*b.z + a.w*b.w;
}

__global__ __launch_bounds__(NT, 2) void lstm2_kernel(
    const float* __restrict__ input,
    const float* __restrict__ Wih1, const float* __restrict__ Whh1,
    const float* __restrict__ bih1, const float* __restrict__ bhh1,
    const float* __restrict__ Wih2, const float* __restrict__ Whh2,
    const float* __restrict__ bih2, const float* __restrict__ bhh2,
    const float* __restrict__ Wlin, const float* __restrict__ blin,
    float* __restrict__ out, float* __restrict__ ws)
{
  // hvec chunked layout: chunk j (j=0..3) = words [j*256, j*256+256):
  //   chunk0: h1 units {8p..8p+3} at word 4p   chunk1: h1 units {8p+4..8p+7}
  //   chunk2: h2 units {8p..8p+3}              chunk3: h2 units {8p+4..8p+7}
  // Producer lane p writes 4xb128 at word j*256+4p; consumer lane sg reads the
  // same addresses -> both sides lane-contiguous -> conflict-free.
  __shared__ __align__(16) float hvec[1024];
  __shared__ __align__(16) float xrow[TT];
  __shared__ float part1[64*33];   // [seg][row], stride 33 (2-way max = free)
  __shared__ float part2[64*33];
  __shared__ float p1b[8*33];
  __shared__ float p2b[8*33];
  __shared__ float xslot;

  float* comm = ws;                // [2][G][LINEF]

  const int t  = threadIdx.x;
  const int wg = blockIdx.x;
  const int rg = t >> 6;           // wave id 0..7
  const int sg = t & 63;           // lane

  ((float2*)xrow)[t] = ((const float2*)(input + 255*TT))[t];

  // ---- weight preload: wg owns hidden units [wg*8, wg*8+8) of both layers.
  // Row r = q*8+u (gate q, unit u) -> global row q*512 + wg*8 + u.
  // Lane sg covers cols [8sg, 8sg+8) of Whh1 (L1) and of Wih2 & Whh2 (L2).
  float4 w1[4][2], w2[4][4];
  #pragma unroll
  for (int k=0;k<4;k++){
    const int r = rg*4 + k;
    const int R = (r>>3)*HD + wg*8 + (r&7);
    const float* pa = Whh1 + R*HD + sg*8;
    w1[k][0] = *(const float4*)(pa);
    w1[k][1] = *(const float4*)(pa+4);
    const float* pb = Wih2 + R*HD + sg*8;
    const float* pc = Whh2 + R*HD + sg*8;
    w2[k][0] = *(const float4*)(pb);
    w2[k][1] = *(const float4*)(pb+4);
    w2[k][2] = *(const float4*)(pc);
    w2[k][3] = *(const float4*)(pc+4);
  }

  // combine lanes: t<8 -> L1 unit t; t in [8,16) -> L2 unit t-8
  float bias[4]={0,0,0,0}, wx[4]={0,0,0,0};
  float cst = 0.f;      // persistent cell state
  float hcur = 0.f;     // last h value this lane produced (re-published each tick)
  if (t < 8){
    #pragma unroll
    for (int q=0;q<4;q++){
      int R = q*HD + wg*8 + t;
      bias[q] = bih1[R] + bhh1[R];
      wx[q]   = Wih1[R];
    }
  } else if (t < 16){
    #pragma unroll
    for (int q=0;q<4;q++){
      int R = q*HD + wg*8 + (t-8);
      bias[q] = bih2[R] + bhh2[R];
    }
  }
  float4 wl0={0,0,0,0}, wl1={0,0,0,0};
  if (t < 64){
    wl0 = *(const float4*)(Wlin + t*8);
    wl1 = *(const float4*)(Wlin + t*8 + 4);
  }
  const float blin0 = blin[0];

  // ---- consume tick g: wave 0 polls 64 lines, stages data into hvec ----
  auto poll_stage = [&](unsigned g){
    if (t < 64){
      float* base = comm + (g & 1u)*SLOTF + t*LINEF;
      unsigned* gp = (unsigned*)(base + 16);
      while (__hip_atomic_load(gp, __ATOMIC_RELAXED, AS) < g) {}
      __builtin_amdgcn_fence(__ATOMIC_ACQUIRE, "agent");
      const float4* dp = (const float4*)base;
      float4 a = dp[0], b = dp[1], c = dp[2], d = dp[3];
      float4* hv = (float4*)hvec;
      hv[0*64 + t] = a;
      hv[1*64 + t] = b;
      hv[2*64 + t] = c;
      hv[3*64 + t] = d;
    }
    __syncthreads();
  };

  // ---- partial dots (all threads), conflict-free b128 hvec reads ----
  auto dots = [&](){
    const float4* hv = (const float4*)hvec;
    const float4 c0 = hv[0*64 + sg];
    const float4 c1 = hv[1*64 + sg];
    const float4 c2 = hv[2*64 + sg];
    const float4 c3 = hv[3*64 + sg];
    #pragma unroll
    for (int k=0;k<4;k++){
      part1[sg*33 + rg*4 + k] = dot4(w1[k][0],c0) + dot4(w1[k][1],c1);
      part2[sg*33 + rg*4 + k] = dot4(w2[k][0],c0) + dot4(w2[k][1],c1)
                              + dot4(w2[k][2],c2) + dot4(w2[k][3],c3);
    }
  };

  auto reduce_s1 = [&](){
    const int rr = t & 31;
    const int g8 = (t >> 5) & 7;
    if (t < 256){
      float s = 0.f;
      #pragma unroll
      for (int i=0;i<8;i++) s += part1[(g8*8+i)*33 + rr];
      p1b[g8*33 + rr] = s;
    } else {
      float s = 0.f;
      #pragma unroll
      for (int i=0;i<8;i++) s += part2[(g8*8+i)*33 + rr];
      p2b[g8*33 + rr] = s;
    }
  };

  // ---- tail (wave 0): final reduce, gates, publish line for tick g+1 ----
  auto tail = [&](unsigned g, bool d1, bool d2, float xv){
    if (t < 64){
      float rsum;
      if (t < 32){
        float s = 0.f;
        #pragma unroll
        for (int gi=0;gi<8;gi++) s += p1b[gi*33 + t];
        rsum = s;
      } else {
        float s = 0.f;
        #pragma unroll
        for (int gi=0;gi<8;gi++) s += p2b[gi*33 + (t-32)];
        rsum = s;
      }
      const int u  = t & 7;
      const int s0 = (t < 8) ? t : (32 + u);     // lanes >=16: don't-care
      float pi = __shfl(rsum, s0,      64);
      float pf = __shfl(rsum, s0 + 8,  64);
      float pg = __shfl(rsum, s0 + 16, 64);
      float po = __shfl(rsum, s0 + 24, 64);
      const bool act = (t < 8) ? d1 : ((t < 16) ? d2 : false);
      if (act){
        if (t < 8){
          pi += xv*wx[0] + bias[0];
          pf += xv*wx[1] + bias[1];
          pg += xv*wx[2] + bias[2];
          po += xv*wx[3] + bias[3];
        } else {
          pi += bias[0]; pf += bias[1]; pg += bias[2]; po += bias[3];
        }
        cst  = sigf(pf)*cst + sigf(pi)*tanhf(pg);
        hcur = sigf(po)*tanhf(cst);
      }
      float* nb = comm + ((g+1u) & 1u)*SLOTF + wg*LINEF;
      if (t < 16) nb[t] = hcur;
      if (t == 0)
        __hip_atomic_store((unsigned*)(nb + 16), g + 1u, __ATOMIC_RELEASE, AS);
    }
  };

  // o = Wlin . h2 + blin from staged hvec chunks 2/3 (deterministic, all WGs)
  auto computeO = [&](int oi){
    if (t < 64){
      const float4* hv = (const float4*)hvec;
      float s = dot4(wl0, hv[2*64 + t]) + dot4(wl1, hv[3*64 + t]);
      #pragma unroll
      for (int m=1;m<64;m<<=1) s += __shfl_xor(s, m, 64);
      if (t == 0){
        const float o = s + blin0;
        xslot = o;
        if (wg == 0) out[oi] = o;
      }
    }
  };

  __syncthreads();   // xrow staged

  unsigned g = 0;

  // ---- teacher: tick g computes L1 step g || L2 step g-1 ----
  for (int tk=0; tk<TT; ++tk, ++g){
    poll_stage(g);                       // hvec = [h1_{g-1} | h2_{g-2}]
    dots();
    __syncthreads();
    reduce_s1();
    __syncthreads();
    tail(g, true, tk >= 1, xrow[tk]);    // publish [h1_g | h2_{g-1}]
  }

  // ---- drain: L2 step 1023 (g = 1024) ----
  poll_stage(g);                         // [h1_1023 | h2_1022]
  dots();
  __syncthreads();
  reduce_s1();
  __syncthreads();
  tail(g, false, true, 0.f);             // publish [h1_1023 | h2_1023]
  ++g;

  // ---- AR: steps s = 1024..1086, 2 ticks each ----
  for (int s=TT; s<TT+PRED-1; ++s){
    // tick B: o_{s-1} (emit out[s-TT]) + L1 step s
    poll_stage(g);                       // [h1_{s-1} | h2_{s-1}]
    computeO(s - TT);                    // writes xslot (LDS), out if wg0
    dots();
    __syncthreads();
    reduce_s1();
    __syncthreads();
    tail(g, true, false, xslot);         // publish [h1_s | h2_{s-1}]
    ++g;

    // tick A: L2 step s
    poll_stage(g);                       // [h1_s | h2_{s-1}]
    dots();
    __syncthreads();
    reduce_s1();
    __syncthreads();
    tail(g, false, true, 0.f);           // publish [h1_s | h2_s]
    ++g;
  }

  // ---- final output o_1086 (g = 1151) ----
  poll_stage(g);                         // [h1_1086 | h2_1086]
  computeO(PRED - 1);
}

extern "C" void kernel_launch(void* const* d_in, const int* in_sizes, int n_in,
                              void* d_out, int out_size, void* d_ws, size_t ws_size,
                              hipStream_t stream) {
  const float* input = (const float*)d_in[0];
  // d_in[1] = pred_len (fixed 64, baked in)
  const float* Wih1 = (const float*)d_in[2];
  const float* Whh1 = (const float*)d_in[3];
  const float* bih1 = (const float*)d_in[4];
  const float* bhh1 = (const float*)d_in[5];
  const float* Wih2 = (const float*)d_in[6];
  const float* Whh2 = (const float*)d_in[7];
  const float* bih2 = (const float*)d_in[8];
  const float* bhh2 = (const float*)d_in[9];
  const float* Wlin = (const float*)d_in[10];
  const float* blin = (const float*)d_in[11];

  // zero the comm lines (gen words + initial h = 0); ws re-poisoned per launch
  hipMemsetAsync(d_ws, 0, 2 * SLOTF * sizeof(float), stream);

  lstm2_kernel<<<dim3(G), dim3(NT), 0, stream>>>(
      input, Wih1, Whh1, bih1, bhh1, Wih2, Whh2, bih2, bhh2, Wlin, blin,
      (float*)d_out, (float*)d_ws);
}

// Round 4
// 3541.714 us; speedup vs baseline: 1.7999x; 1.1027x over previous
//
#include <hip/hip_runtime.h>
#include <math.h>

// 2-layer LSTM (H=512), T=1024 teacher steps + 64 AR steps; only batch row 255
// reaches the output -> single-sequence LSTM. Weights register-resident across
// 64 persistent WGs. Per-tick all-to-all h exchange via data-carrying lines:
// producer publishes 16 floats (relaxed agent-scope atomic b64 stores) + one
// RELEASE store of a monotone generation word; consumers poll gen RELAXED and
// read the data with relaxed agent-scope atomic b64 loads whose ADDRESS
// depends on the observed gen value (opaque asm) -> compiler cannot hoist the
// data loads above the poll, hardware cannot issue them before gen is
// observed. Producer's release guarantees data-at-IC before gen-at-IC, so
// consume-ordering suffices: no acquire fence, no cache-invalidation storm.
// Intra-WG: 64-way column reduction as wave-internal shuffle reduce-scatter
// (10 shuffle+adds for 8 rows) -> 8 floats/wave to LDS -> wave 0 applies
// gates and publishes. 2 __syncthreads per tick.

#define G     64      // workgroups
#define NT    512     // threads/wg
#define HD    512     // hidden
#define TT    1024    // teacher steps
#define PRED  64      // prediction length
#define LINEF 64      // floats per comm line (256 B): d[16] | gen @ word 16
#define SLOTF (G*LINEF)
#define AS    __HIP_MEMORY_SCOPE_AGENT

typedef unsigned long long u64;

__device__ __forceinline__ float sigf(float x){ return 1.0f/(1.0f+expf(-x)); }
__device__ __forceinline__ float dot4(float4 a, float4 b){
  return a.x*b.x + a.y*b.y + a.z*b.z + a.w*b.w;
}

__global__ __launch_bounds__(NT, 1) void lstm2_kernel(
    const float* __restrict__ input,
    const float* __restrict__ Wih1, const float* __restrict__ Whh1,
    const float* __restrict__ bih1, const float* __restrict__ bhh1,
    const float* __restrict__ Wih2, const float* __restrict__ Whh2,
    const float* __restrict__ bih2, const float* __restrict__ bhh2,
    const float* __restrict__ Wlin, const float* __restrict__ blin,
    float* __restrict__ out, float* __restrict__ ws)
{
  // hvec chunk c (c=0..3) = words [c*256, c*256+256):
  //   c0: h1 units 8t..8t+3 of WG t   c1: h1 units 8t+4..8t+7
  //   c2: h2 units 8t..8t+3           c3: h2 units 8t+4..8t+7
  __shared__ __align__(16) float hvec[1024];
  __shared__ __align__(16) float xrow[TT];
  __shared__ float pre[64];     // [0..31]=L1 rows (gate q*8+unit u), [32..63]=L2

  float* comm = ws;             // [2][G][LINEF]

  const int t  = threadIdx.x;
  const int wg = blockIdx.x;
  const int rg = t >> 6;        // wave id 0..7
  const int sg = t & 63;        // lane

  ((float2*)xrow)[t] = ((const float2*)(input + 255*TT))[t];

  // ---- weight preload: wg owns hidden units [wg*8, wg*8+8) of both layers.
  // Row r = rg*4+k (r in 0..31: gate q=r>>3, unit u=r&7) -> global row
  // q*512 + wg*8 + u. Lane sg covers cols [8sg, 8sg+8).
  float4 w1[4][2], w2[4][4];
  #pragma unroll
  for (int k=0;k<4;k++){
    const int r = rg*4 + k;
    const int R = (r>>3)*HD + wg*8 + (r&7);
    const float* pa = Whh1 + R*HD + sg*8;
    w1[k][0] = *(const float4*)(pa);
    w1[k][1] = *(const float4*)(pa+4);
    const float* pb = Wih2 + R*HD + sg*8;
    const float* pc = Whh2 + R*HD + sg*8;
    w2[k][0] = *(const float4*)(pb);
    w2[k][1] = *(const float4*)(pb+4);
    w2[k][2] = *(const float4*)(pc);
    w2[k][3] = *(const float4*)(pc+4);
  }

  // combine lanes (wave 0): t<8 -> L1 unit t; t in [8,16) -> L2 unit t-8
  float bias[4]={0,0,0,0}, wx[4]={0,0,0,0};
  float cst  = 0.f;     // persistent cell state
  float hcur = 0.f;     // last h this lane produced (re-published every tick)
  if (t < 8){
    #pragma unroll
    for (int q=0;q<4;q++){
      int R = q*HD + wg*8 + t;
      bias[q] = bih1[R] + bhh1[R];
      wx[q]   = Wih1[R];
    }
  } else if (t < 16){
    #pragma unroll
    for (int q=0;q<4;q++){
      int R = q*HD + wg*8 + (t-8);
      bias[q] = bih2[R] + bhh2[R];
    }
  }
  float4 wl0={0,0,0,0}, wl1={0,0,0,0};
  if (t < 64){
    wl0 = *(const float4*)(Wlin + t*8);
    wl1 = *(const float4*)(Wlin + t*8 + 4);
  }
  const float blin0 = blin[0];

  // ---- consume tick g: wave 0 polls 64 lines, stages into hvec.
  // Data loads carry an address dependency on the observed gen value so they
  // cannot be hoisted (compiler) or issued early (hardware). No fence.
  auto poll_stage = [&](unsigned g){
    if (t < 64){
      float* base = comm + (g & 1u)*SLOTF + t*LINEF;
      const unsigned* gp = (const unsigned*)(base + 16);
      unsigned v;
      do { v = __hip_atomic_load(gp, __ATOMIC_RELAXED, AS); } while (v < g);
      unsigned dep = v >> 31;            // always 0 (gen <= 1151), unprovable
      asm volatile("" : "+v"(dep));      // opaque -> real addr dependency
      const u64* dq = (const u64*)(base + dep);
      u64 q[8];
      #pragma unroll
      for (int j=0;j<8;j++) q[j] = __hip_atomic_load(dq + j, __ATOMIC_RELAXED, AS);
      float2* hv2 = (float2*)hvec;
      #pragma unroll
      for (int c=0;c<4;c++){
        hv2[c*128 + 2*t    ] = __builtin_bit_cast(float2, q[2*c]);
        hv2[c*128 + 2*t + 1] = __builtin_bit_cast(float2, q[2*c+1]);
      }
    }
    __syncthreads();
  };

  // ---- dots + wave-internal reduce-scatter; writes 8 row-sums/wave to pre ----
  auto dots_reduce = [&](){
    const float4* hv = (const float4*)hvec;
    const float4 c0 = hv[0*64 + sg];
    const float4 c1 = hv[1*64 + sg];
    const float4 c2 = hv[2*64 + sg];
    const float4 c3 = hv[3*64 + sg];
    float v[8];
    #pragma unroll
    for (int k=0;k<4;k++){
      v[k]   = dot4(w1[k][0],c0) + dot4(w1[k][1],c1);
      v[4+k] = dot4(w2[k][0],c0) + dot4(w2[k][1],c1)
             + dot4(w2[k][2],c2) + dot4(w2[k][3],c3);
    }
    const int b0 = sg & 1, b1 = (sg>>1)&1, b2 = (sg>>2)&1;
    float k4[4];
    #pragma unroll
    for (int k=0;k<4;k++){
      float x = b0 ? v[k] : v[k+4];
      float y = __shfl_xor(x, 1, 64);
      k4[k] = (b0 ? v[k+4] : v[k]) + y;
    }
    float k2[2];
    #pragma unroll
    for (int k=0;k<2;k++){
      float x = b1 ? k4[k] : k4[k+2];
      float y = __shfl_xor(x, 2, 64);
      k2[k] = (b1 ? k4[k+2] : k4[k]) + y;
    }
    float k1;
    {
      float x = b2 ? k2[0] : k2[1];
      float y = __shfl_xor(x, 4, 64);
      k1 = (b2 ? k2[1] : k2[0]) + y;
    }
    k1 += __shfl_xor(k1, 8, 64);
    k1 += __shfl_xor(k1, 16, 64);
    k1 += __shfl_xor(k1, 32, 64);
    if (sg < 8){
      const int j = b0*4 + b1*2 + b2;   // value index this lane holds
      if (j < 4) pre[rg*4 + j]        = k1;   // L1 row rg*4+j
      else       pre[32 + rg*4 + j-4] = k1;   // L2 row rg*4+(j-4)
    }
  };

  // ---- tail (wave 0): gate math + publish line for tick g+1 ----
  auto tail = [&](unsigned g, bool d1, bool d2, float xv){
    if (rg == 0){
      const float rsum = pre[t];
      const int u  = t & 7;
      const int s0 = (t < 8) ? t : (32 + u);   // lanes >=16: don't-care
      float pi = __shfl(rsum, s0,      64);
      float pf = __shfl(rsum, s0 + 8,  64);
      float pg = __shfl(rsum, s0 + 16, 64);
      float po = __shfl(rsum, s0 + 24, 64);
      const bool act = (t < 8) ? d1 : ((t < 16) ? d2 : false);
      if (act){
        if (t < 8){
          pi += xv*wx[0] + bias[0];
          pf += xv*wx[1] + bias[1];
          pg += xv*wx[2] + bias[2];
          po += xv*wx[3] + bias[3];
        } else {
          pi += bias[0]; pf += bias[1]; pg += bias[2]; po += bias[3];
        }
        cst  = sigf(pf)*cst + sigf(pi)*tanhf(pg);
        hcur = sigf(po)*tanhf(cst);
      }
      // pack hcur (lanes 0..15) into float2s with ALL wave-0 lanes active
      float lo = __shfl(hcur, 2*(t & 7),     64);
      float hi = __shfl(hcur, 2*(t & 7) + 1, 64);
      float* nb = comm + ((g+1u) & 1u)*SLOTF + wg*LINEF;
      if (t < 8){
        float2 fv; fv.x = lo; fv.y = hi;
        __hip_atomic_store((u64*)nb + t, __builtin_bit_cast(u64, fv),
                           __ATOMIC_RELAXED, AS);
      }
      if (t == 0)
        __hip_atomic_store((unsigned*)(nb + 16), g + 1u, __ATOMIC_RELEASE, AS);
    }
  };

  // o = Wlin . h2 + blin from hvec chunks 2/3; result in ALL wave-0 lanes
  auto computeO = [&](int oi, float& xv){
    if (rg == 0){
      const float4* hv = (const float4*)hvec;
      float s = dot4(wl0, hv[2*64 + t]) + dot4(wl1, hv[3*64 + t]);
      #pragma unroll
      for (int m=1;m<64;m<<=1) s += __shfl_xor(s, m, 64);
      xv = s + blin0;
      if (wg == 0 && t == 0) out[oi] = xv;
    }
  };

  __syncthreads();   // xrow staged

  unsigned g = 0;

  // ---- teacher: tick g computes L1 step g || L2 step g-1 ----
  for (int tk=0; tk<TT; ++tk, ++g){
    poll_stage(g);                       // hvec = [h1_{g-1} | h2_{g-2}]
    dots_reduce();
    __syncthreads();
    tail(g, true, tk >= 1, xrow[tk]);    // publish [h1_g | h2_{g-1}]
  }

  // ---- drain: L2 step 1023 ----
  poll_stage(g);                         // [h1_1023 | h2_1022]
  dots_reduce();
  __syncthreads();
  tail(g, false, true, 0.f);             // publish [h1_1023 | h2_1023]
  ++g;

  // ---- AR: steps s = 1024..1086, 2 ticks each ----
  for (int s=TT; s<TT+PRED-1; ++s){
    poll_stage(g);                       // [h1_{s-1} | h2_{s-1}]
    float xv = 0.f;
    computeO(s - TT, xv);                // emit out[s-TT] (o_{s-1})
    dots_reduce();
    __syncthreads();
    tail(g, true, false, xv);            // publish [h1_s | h2_{s-1}]
    ++g;

    poll_stage(g);                       // [h1_s | h2_{s-1}]
    dots_reduce();
    __syncthreads();
    tail(g, false, true, 0.f);           // publish [h1_s | h2_s]
    ++g;
  }

  // ---- final output o_1086 ----
  poll_stage(g);                         // [h1_1086 | h2_1086]
  float xv;
  computeO(PRED - 1, xv);
}

extern "C" void kernel_launch(void* const* d_in, const int* in_sizes, int n_in,
                              void* d_out, int out_size, void* d_ws, size_t ws_size,
                              hipStream_t stream) {
  const float* input = (const float*)d_in[0];
  // d_in[1] = pred_len (fixed 64, baked in)
  const float* Wih1 = (const float*)d_in[2];
  const float* Whh1 = (const float*)d_in[3];
  const float* bih1 = (const float*)d_in[4];
  const float* bhh1 = (const float*)d_in[5];
  const float* Wih2 = (const float*)d_in[6];
  const float* Whh2 = (const float*)d_in[7];
  const float* bih2 = (const float*)d_in[8];
  const float* bhh2 = (const float*)d_in[9];
  const float* Wlin = (const float*)d_in[10];
  const float* blin = (const float*)d_in[11];

  // zero the comm lines (gen words + initial h = 0); ws re-poisoned per launch
  hipMemsetAsync(d_ws, 0, 2 * SLOTF * sizeof(float), stream);

  lstm2_kernel<<<dim3(G), dim3(NT), 0, stream>>>(
      input, Wih1, Whh1, bih1, bhh1, Wih2, Whh2, bih2, bhh2, Wlin, blin,
      (float*)d_out, (float*)d_ws);
}

// Round 5
// 2079.026 us; speedup vs baseline: 3.0663x; 1.7035x over previous
//
#include <hip/hip_runtime.h>
#include <math.h>

// 2-layer LSTM (H=512), T=1024 teacher steps + 64 AR steps; only batch row 255
// reaches the output -> single-sequence LSTM. Weights register-resident across
// 64 persistent WGs. Per-tick all-to-all h exchange via SELF-VALIDATING pairs:
// each published value is a u64 (gen<<32 | bitcast(h)). A WG's line is 16
// pairs = 128 B. Producers: 16 relaxed agent-scope b64 atomic stores (no gen
// word, no release). Consumers: all 512 threads spin on relaxed b64 atomic
// loads (8 lanes/line, 2 pairs/lane) until gen fields == g -> detection and
// data arrive in ONE IC round-trip (R4 needed two: gen poll + addr-dependent
// data read). 8B pair atomicity makes torn reads impossible; slot-reuse is
// safe by the same value-dependency causality as R2/R4 (deterministic there).
// Intra-WG: wave-internal shuffle reduce-scatter -> 8 floats/wave to LDS ->
// wave 0 applies gates (fast v_exp/v_rcp sigmoid+tanh) and publishes.
// 2 __syncthreads per tick.

#define G     64      // workgroups
#define NT    512     // threads/wg
#define HD    512     // hidden
#define TT    1024    // teacher steps
#define PRED  64      // prediction length
#define LINEF 64      // floats per comm line slot (256 B); pairs in words 0..31
#define SLOTF (G*LINEF)
#define AS    __HIP_MEMORY_SCOPE_AGENT

typedef unsigned long long u64;

#define LOG2E  1.44269504088896340736f

__device__ __forceinline__ float sigf(float x){
  // 1/(1+exp(-x)) via v_exp_f32 + v_rcp_f32 (err ~1e-6, threshold 3.6e-4)
  return __builtin_amdgcn_rcpf(1.0f + __builtin_amdgcn_exp2f(-LOG2E * x));
}
__device__ __forceinline__ float tanhf_fast(float x){
  // 1 - 2/(exp(2x)+1); saturates correctly for |x| large
  float e = __builtin_amdgcn_exp2f(2.0f * LOG2E * x);
  return 1.0f - 2.0f * __builtin_amdgcn_rcpf(e + 1.0f);
}
__device__ __forceinline__ float dot4(float4 a, float4 b){
  return a.x*b.x + a.y*b.y + a.z*b.z + a.w*b.w;
}

__global__ __launch_bounds__(NT, 1) void lstm2_kernel(
    const float* __restrict__ input,
    const float* __restrict__ Wih1, const float* __restrict__ Whh1,
    const float* __restrict__ bih1, const float* __restrict__ bhh1,
    const float* __restrict__ Wih2, const float* __restrict__ Whh2,
    const float* __restrict__ bih2, const float* __restrict__ bhh2,
    const float* __restrict__ Wlin, const float* __restrict__ blin,
    float* __restrict__ out, float* __restrict__ ws)
{
  // hvec chunk c (c=0..3) = words [c*256, c*256+256):
  //   c0: h1 units {8w..8w+3} of WG w at word 4w   c1: h1 units {8w+4..8w+7}
  //   c2: h2 units {8w..8w+3}                      c3: h2 units {8w+4..8w+7}
  // dots lane sg reads hv4[c*64+sg] -> consecutive lanes, consecutive 16B:
  // conflict-free.
  __shared__ __align__(16) float hvec[1024];
  __shared__ __align__(16) float xrow[TT];
  __shared__ float pre[64];     // [0..31]=L1 rows (gate q*8+unit u), [32..63]=L2

  float* comm = ws;             // [2][G][LINEF]

  const int t  = threadIdx.x;
  const int wg = blockIdx.x;
  const int rg = t >> 6;        // wave id 0..7
  const int sg = t & 63;        // lane

  ((float2*)xrow)[t] = ((const float2*)(input + 255*TT))[t];

  // ---- weight preload: wg owns hidden units [wg*8, wg*8+8) of both layers.
  // Row r = rg*4+k (r in 0..31: gate q=r>>3, unit u=r&7) -> global row
  // q*512 + wg*8 + u. Lane sg covers cols [8sg, 8sg+8).
  float4 w1[4][2], w2[4][4];
  #pragma unroll
  for (int k=0;k<4;k++){
    const int r = rg*4 + k;
    const int R = (r>>3)*HD + wg*8 + (r&7);
    const float* pa = Whh1 + R*HD + sg*8;
    w1[k][0] = *(const float4*)(pa);
    w1[k][1] = *(const float4*)(pa+4);
    const float* pb = Wih2 + R*HD + sg*8;
    const float* pc = Whh2 + R*HD + sg*8;
    w2[k][0] = *(const float4*)(pb);
    w2[k][1] = *(const float4*)(pb+4);
    w2[k][2] = *(const float4*)(pc);
    w2[k][3] = *(const float4*)(pc+4);
  }

  // combine lanes (wave 0): t<8 -> L1 unit t; t in [8,16) -> L2 unit t-8
  float bias[4]={0,0,0,0}, wx[4]={0,0,0,0};
  float cst  = 0.f;     // persistent cell state
  float hcur = 0.f;     // last h this lane produced (re-published every tick)
  if (t < 8){
    #pragma unroll
    for (int q=0;q<4;q++){
      int R = q*HD + wg*8 + t;
      bias[q] = bih1[R] + bhh1[R];
      wx[q]   = Wih1[R];
    }
  } else if (t < 16){
    #pragma unroll
    for (int q=0;q<4;q++){
      int R = q*HD + wg*8 + (t-8);
      bias[q] = bih2[R] + bhh2[R];
    }
  }
  float4 wl0={0,0,0,0}, wl1={0,0,0,0};
  if (t < 64){
    wl0 = *(const float4*)(Wlin + t*8);
    wl1 = *(const float4*)(Wlin + t*8 + 4);
  }
  const float blin0 = blin[0];

  // ---- consume tick g: all 512 threads. Lane t owns pairs {2j,2j+1} of line
  // w (w=t>>3, j=t&7). Spin until both pairs carry gen g; value is in-pair ->
  // single IC round-trip, no fence, no address-dependency second RT.
  auto poll_stage = [&](unsigned g){
    const int w = t >> 3, j = t & 7;
    const u64* dq = (const u64*)(comm + (g & 1u)*SLOTF + w*LINEF) + 2*j;
    u64 q0, q1;
    do {
      q0 = __hip_atomic_load(dq,     __ATOMIC_RELAXED, AS);
      q1 = __hip_atomic_load(dq + 1, __ATOMIC_RELAXED, AS);
    } while ((unsigned)(q0 >> 32) != g || (unsigned)(q1 >> 32) != g);
    // pair i of line w: i<8 -> h1 unit w*8+i ; i>=8 -> h2 unit w*8+(i-8)
    // chunked hvec address for pair pair-index i: chunk (i>>2)+ (h1:0/1, h2:2/3)
    // here i=2j (and 2j+1 contiguous, same chunk since 2j,2j+1 share i>>2):
    const int c  = j >> 1;                   // 2j>>2 == j>>1 (chunks 0..3)
    const int wd = c*256 + 4*w + 2*(j & 1);  // word offset in hvec
    float2 fv;
    fv.x = __builtin_bit_cast(float, (unsigned)q0);
    fv.y = __builtin_bit_cast(float, (unsigned)q1);
    *(float2*)(hvec + wd) = fv;
    __syncthreads();
  };

  // ---- dots + wave-internal reduce-scatter; writes 8 row-sums/wave to pre ----
  auto dots_reduce = [&](){
    const float4* hv = (const float4*)hvec;
    const float4 c0 = hv[0*64 + sg];
    const float4 c1 = hv[1*64 + sg];
    const float4 c2 = hv[2*64 + sg];
    const float4 c3 = hv[3*64 + sg];
    float v[8];
    #pragma unroll
    for (int k=0;k<4;k++){
      v[k]   = dot4(w1[k][0],c0) + dot4(w1[k][1],c1);
      v[4+k] = dot4(w2[k][0],c0) + dot4(w2[k][1],c1)
             + dot4(w2[k][2],c2) + dot4(w2[k][3],c3);
    }
    const int b0 = sg & 1, b1 = (sg>>1)&1, b2 = (sg>>2)&1;
    float k4[4];
    #pragma unroll
    for (int k=0;k<4;k++){
      float x = b0 ? v[k] : v[k+4];
      float y = __shfl_xor(x, 1, 64);
      k4[k] = (b0 ? v[k+4] : v[k]) + y;
    }
    float k2[2];
    #pragma unroll
    for (int k=0;k<2;k++){
      float x = b1 ? k4[k] : k4[k+2];
      float y = __shfl_xor(x, 2, 64);
      k2[k] = (b1 ? k4[k+2] : k4[k]) + y;
    }
    float k1;
    {
      float x = b2 ? k2[0] : k2[1];
      float y = __shfl_xor(x, 4, 64);
      k1 = (b2 ? k2[1] : k2[0]) + y;
    }
    k1 += __shfl_xor(k1, 8, 64);
    k1 += __shfl_xor(k1, 16, 64);
    k1 += __shfl_xor(k1, 32, 64);
    if (sg < 8){
      const int j = b0*4 + b1*2 + b2;   // value index this lane holds
      if (j < 4) pre[rg*4 + j]        = k1;   // L1 row rg*4+j
      else       pre[32 + rg*4 + j-4] = k1;   // L2 row rg*4+(j-4)
    }
  };

  // ---- tail (wave 0): gate math + publish self-validating pairs for g+1 ----
  auto tail = [&](unsigned g, bool d1, bool d2, float xv){
    if (rg == 0){
      const float rsum = pre[t];
      const int u  = t & 7;
      const int s0 = (t < 8) ? t : (32 + u);   // lanes >=16: don't-care
      float pi = __shfl(rsum, s0,      64);
      float pf = __shfl(rsum, s0 + 8,  64);
      float pg = __shfl(rsum, s0 + 16, 64);
      float po = __shfl(rsum, s0 + 24, 64);
      const bool act = (t < 8) ? d1 : ((t < 16) ? d2 : false);
      if (act){
        if (t < 8){
          pi += xv*wx[0] + bias[0];
          pf += xv*wx[1] + bias[1];
          pg += xv*wx[2] + bias[2];
          po += xv*wx[3] + bias[3];
        } else {
          pi += bias[0]; pf += bias[1]; pg += bias[2]; po += bias[3];
        }
        cst  = sigf(pf)*cst + sigf(pi)*tanhf_fast(pg);
        hcur = sigf(po)*tanhf_fast(cst);
      }
      if (t < 16){
        u64 pr = ((u64)(g + 1u) << 32) | (u64)__builtin_bit_cast(unsigned, hcur);
        u64* nb = (u64*)(comm + ((g+1u) & 1u)*SLOTF + wg*LINEF);
        __hip_atomic_store(nb + t, pr, __ATOMIC_RELAXED, AS);
      }
    }
  };

  // o = Wlin . h2 + blin from hvec chunks 2/3; result in ALL wave-0 lanes
  auto computeO = [&](int oi, float& xv){
    if (rg == 0){
      const float4* hv = (const float4*)hvec;
      float s = dot4(wl0, hv[2*64 + t]) + dot4(wl1, hv[3*64 + t]);
      #pragma unroll
      for (int m=1;m<64;m<<=1) s += __shfl_xor(s, m, 64);
      xv = s + blin0;
      if (wg == 0 && t == 0) out[oi] = xv;
    }
  };

  __syncthreads();   // xrow staged

  unsigned g = 0;

  // ---- teacher: tick g computes L1 step g || L2 step g-1 ----
  for (int tk=0; tk<TT; ++tk, ++g){
    poll_stage(g);                       // hvec = [h1_{g-1} | h2_{g-2}]
    dots_reduce();
    __syncthreads();
    tail(g, true, tk >= 1, xrow[tk]);    // publish [h1_g | h2_{g-1}] pairs
  }

  // ---- drain: L2 step 1023 ----
  poll_stage(g);                         // [h1_1023 | h2_1022]
  dots_reduce();
  __syncthreads();
  tail(g, false, true, 0.f);             // publish [h1_1023 | h2_1023]
  ++g;

  // ---- AR: steps s = 1024..1086, 2 ticks each ----
  for (int s=TT; s<TT+PRED-1; ++s){
    poll_stage(g);                       // [h1_{s-1} | h2_{s-1}]
    float xv = 0.f;
    computeO(s - TT, xv);                // emit out[s-TT] (o_{s-1})
    dots_reduce();
    __syncthreads();
    tail(g, true, false, xv);            // publish [h1_s | h2_{s-1}]
    ++g;

    poll_stage(g);                       // [h1_s | h2_{s-1}]
    dots_reduce();
    __syncthreads();
    tail(g, false, true, 0.f);           // publish [h1_s | h2_s]
    ++g;
  }

  // ---- final output o_1086 ----
  poll_stage(g);                         // [h1_1086 | h2_1086]
  float xv;
  computeO(PRED - 1, xv);
}

extern "C" void kernel_launch(void* const* d_in, const int* in_sizes, int n_in,
                              void* d_out, int out_size, void* d_ws, size_t ws_size,
                              hipStream_t stream) {
  const float* input = (const float*)d_in[0];
  // d_in[1] = pred_len (fixed 64, baked in)
  const float* Wih1 = (const float*)d_in[2];
  const float* Whh1 = (const float*)d_in[3];
  const float* bih1 = (const float*)d_in[4];
  const float* bhh1 = (const float*)d_in[5];
  const float* Wih2 = (const float*)d_in[6];
  const float* Whh2 = (const float*)d_in[7];
  const float* bih2 = (const float*)d_in[8];
  const float* bhh2 = (const float*)d_in[9];
  const float* Wlin = (const float*)d_in[10];
  const float* blin = (const float*)d_in[11];

  // zero comm: u64 zero pairs == (gen 0, h=0.0f) -> valid initial state
  hipMemsetAsync(d_ws, 0, 2 * SLOTF * sizeof(float), stream);

  lstm2_kernel<<<dim3(G), dim3(NT), 0, stream>>>(
      input, Wih1, Whh1, bih1, bhh1, Wih2, Whh2, bih2, bhh2, Wlin, blin,
      (float*)d_out, (float*)d_ws);
}

// Round 6
// 2065.249 us; speedup vs baseline: 3.0867x; 1.0067x over previous
//
#include <hip/hip_runtime.h>
#include <math.h>

// 2-layer LSTM (H=512), T=1024 teacher steps + 64 AR steps; only batch row 255
// reaches the output -> single-sequence LSTM. Weights register-resident across
// 64 persistent WGs (PINNED via opaque asm: R5's VGPR_Count=88 proved the
// compiler was re-loading all 96 weight VGPRs from L2 every tick ~0.6us).
// Per-tick all-to-all h exchange via SELF-VALIDATING pairs: each published
// value is a u64 (gen<<32 | bitcast(h)); a WG's line is 16 pairs = 128 B.
// Producers: 16 relaxed agent-scope b64 atomic stores. Consumers: all 512
// threads spin on relaxed b64 atomic loads (8 lanes/line, 2 pairs/lane) until
// gen fields == g -> detection and data in ONE IC round-trip. 8B atomicity
// forbids torn reads; slot-reuse safe by value-dependency causality (a
// producer overwrites gen g-1 pairs only after observing gen g everywhere,
// which happens only after everyone's g-1 reads completed).
// Intra-WG: wave-internal shuffle reduce-scatter -> 8 floats/wave to LDS ->
// wave 0 applies gates (fast v_exp/v_rcp sigmoid+tanh) and publishes.
// hvec chunk stride padded 256->264 words: un-padded, the 4 chunks alias to
// the same LDS bank for the staging float2 stores (4-way, 7.4e6 conflicts/run).

#define G     64      // workgroups
#define NT    512     // threads/wg
#define HD    512     // hidden
#define TT    1024    // teacher steps
#define PRED  64      // prediction length
#define LINEF 64      // floats per comm line slot (256 B); pairs in words 0..31
#define SLOTF (G*LINEF)
#define STR   264     // hvec chunk stride in words (256 data + 8 pad banks)
#define AS    __HIP_MEMORY_SCOPE_AGENT

typedef unsigned long long u64;

#define LOG2E  1.44269504088896340736f

// opaque register pin: makes the asm the producer of the value so the
// compiler cannot rematerialize the original global load inside the loop
#define KEEP4(v) asm volatile("" : "+v"(v.x), "+v"(v.y), "+v"(v.z), "+v"(v.w))

__device__ __forceinline__ float sigf(float x){
  // 1/(1+exp(-x)) via v_exp_f32 + v_rcp_f32 (err ~1e-6, threshold 3.6e-4)
  return __builtin_amdgcn_rcpf(1.0f + __builtin_amdgcn_exp2f(-LOG2E * x));
}
__device__ __forceinline__ float tanhf_fast(float x){
  // 1 - 2/(exp(2x)+1); saturates correctly for |x| large
  float e = __builtin_amdgcn_exp2f(2.0f * LOG2E * x);
  return 1.0f - 2.0f * __builtin_amdgcn_rcpf(e + 1.0f);
}
__device__ __forceinline__ float dot4(float4 a, float4 b){
  return a.x*b.x + a.y*b.y + a.z*b.z + a.w*b.w;
}

__global__ __launch_bounds__(NT, 1) void lstm2_kernel(
    const float* __restrict__ input,
    const float* __restrict__ Wih1, const float* __restrict__ Whh1,
    const float* __restrict__ bih1, const float* __restrict__ bhh1,
    const float* __restrict__ Wih2, const float* __restrict__ Whh2,
    const float* __restrict__ bih2, const float* __restrict__ bhh2,
    const float* __restrict__ Wlin, const float* __restrict__ blin,
    float* __restrict__ out, float* __restrict__ ws)
{
  // hvec chunk c (c=0..3) = words [c*STR, c*STR+256):
  //   c0: h1 units {8w..8w+3} of WG w at word 4w   c1: h1 units {8w+4..8w+7}
  //   c2: h2 units {8w..8w+3}                      c3: h2 units {8w+4..8w+7}
  __shared__ __align__(16) float hvec[4*STR];
  __shared__ __align__(16) float xrow[TT];
  __shared__ float pre[64];     // [0..31]=L1 rows (gate q*8+unit u), [32..63]=L2

  float* comm = ws;             // [2][G][LINEF]

  const int t  = threadIdx.x;
  const int wg = blockIdx.x;
  const int rg = t >> 6;        // wave id 0..7
  const int sg = t & 63;        // lane

  ((float2*)xrow)[t] = ((const float2*)(input + 255*TT))[t];

  // ---- weight preload: wg owns hidden units [wg*8, wg*8+8) of both layers.
  // Row r = rg*4+k (r in 0..31: gate q=r>>3, unit u=r&7) -> global row
  // q*512 + wg*8 + u. Lane sg covers cols [8sg, 8sg+8).
  float4 w1[4][2], w2[4][4];
  #pragma unroll
  for (int k=0;k<4;k++){
    const int r = rg*4 + k;
    const int R = (r>>3)*HD + wg*8 + (r&7);
    const float* pa = Whh1 + R*HD + sg*8;
    w1[k][0] = *(const float4*)(pa);
    w1[k][1] = *(const float4*)(pa+4);
    const float* pb = Wih2 + R*HD + sg*8;
    const float* pc = Whh2 + R*HD + sg*8;
    w2[k][0] = *(const float4*)(pb);
    w2[k][1] = *(const float4*)(pb+4);
    w2[k][2] = *(const float4*)(pc);
    w2[k][3] = *(const float4*)(pc+4);
  }
  // pin all 96 weight floats in VGPRs
  #pragma unroll
  for (int k=0;k<4;k++){
    KEEP4(w1[k][0]); KEEP4(w1[k][1]);
    KEEP4(w2[k][0]); KEEP4(w2[k][1]); KEEP4(w2[k][2]); KEEP4(w2[k][3]);
  }

  // combine lanes (wave 0): t<8 -> L1 unit t; t in [8,16) -> L2 unit t-8
  float bias[4]={0,0,0,0}, wx[4]={0,0,0,0};
  float cst  = 0.f;     // persistent cell state
  float hcur = 0.f;     // last h this lane produced (re-published every tick)
  if (t < 8){
    #pragma unroll
    for (int q=0;q<4;q++){
      int R = q*HD + wg*8 + t;
      bias[q] = bih1[R] + bhh1[R];
      wx[q]   = Wih1[R];
    }
  } else if (t < 16){
    #pragma unroll
    for (int q=0;q<4;q++){
      int R = q*HD + wg*8 + (t-8);
      bias[q] = bih2[R] + bhh2[R];
    }
  }
  float4 wl0={0,0,0,0}, wl1={0,0,0,0};
  if (t < 64){
    wl0 = *(const float4*)(Wlin + t*8);
    wl1 = *(const float4*)(Wlin + t*8 + 4);
  }
  const float blin0 = blin[0];

  // ---- consume tick g: all 512 threads. Lane t owns pairs {2j,2j+1} of line
  // w (w=t>>3, j=t&7). Spin until both pairs carry gen g; value is in-pair ->
  // single IC round-trip, no fence, no second RT.
  auto poll_stage = [&](unsigned g){
    const int w = t >> 3, j = t & 7;
    const u64* dq = (const u64*)(comm + (g & 1u)*SLOTF + w*LINEF) + 2*j;
    u64 q0, q1;
    do {
      q0 = __hip_atomic_load(dq,     __ATOMIC_RELAXED, AS);
      q1 = __hip_atomic_load(dq + 1, __ATOMIC_RELAXED, AS);
    } while ((unsigned)(q0 >> 32) != g || (unsigned)(q1 >> 32) != g);
    // pair i of line w: i<8 -> h1 unit w*8+i ; i>=8 -> h2 unit w*8+(i-8)
    // chunk c = (2j)>>2 = j>>1; word-in-chunk = 4w + 2*(j&1)
    const int c  = j >> 1;
    const int wd = c*STR + 4*w + 2*(j & 1);
    float2 fv;
    fv.x = __builtin_bit_cast(float, (unsigned)q0);
    fv.y = __builtin_bit_cast(float, (unsigned)q1);
    *(float2*)(hvec + wd) = fv;
    __syncthreads();
  };

  // ---- dots + wave-internal reduce-scatter; writes 8 row-sums/wave to pre ----
  auto dots_reduce = [&](){
    const float4 c0 = ((const float4*)(hvec + 0*STR))[sg];
    const float4 c1 = ((const float4*)(hvec + 1*STR))[sg];
    const float4 c2 = ((const float4*)(hvec + 2*STR))[sg];
    const float4 c3 = ((const float4*)(hvec + 3*STR))[sg];
    float v[8];
    #pragma unroll
    for (int k=0;k<4;k++){
      v[k]   = dot4(w1[k][0],c0) + dot4(w1[k][1],c1);
      v[4+k] = dot4(w2[k][0],c0) + dot4(w2[k][1],c1)
             + dot4(w2[k][2],c2) + dot4(w2[k][3],c3);
    }
    const int b0 = sg & 1, b1 = (sg>>1)&1, b2 = (sg>>2)&1;
    float k4[4];
    #pragma unroll
    for (int k=0;k<4;k++){
      float x = b0 ? v[k] : v[k+4];
      float y = __shfl_xor(x, 1, 64);
      k4[k] = (b0 ? v[k+4] : v[k]) + y;
    }
    float k2[2];
    #pragma unroll
    for (int k=0;k<2;k++){
      float x = b1 ? k4[k] : k4[k+2];
      float y = __shfl_xor(x, 2, 64);
      k2[k] = (b1 ? k4[k+2] : k4[k]) + y;
    }
    float k1;
    {
      float x = b2 ? k2[0] : k2[1];
      float y = __shfl_xor(x, 4, 64);
      k1 = (b2 ? k2[1] : k2[0]) + y;
    }
    k1 += __shfl_xor(k1, 8, 64);
    k1 += __shfl_xor(k1, 16, 64);
    k1 += __shfl_xor(k1, 32, 64);
    if (sg < 8){
      const int j = b0*4 + b1*2 + b2;   // value index this lane holds
      if (j < 4) pre[rg*4 + j]        = k1;   // L1 row rg*4+j
      else       pre[32 + rg*4 + j-4] = k1;   // L2 row rg*4+(j-4)
    }
  };

  // ---- tail (wave 0): gate math + publish self-validating pairs for g+1 ----
  auto tail = [&](unsigned g, bool d1, bool d2, float xv){
    if (rg == 0){
      const float rsum = pre[t];
      const int u  = t & 7;
      const int s0 = (t < 8) ? t : (32 + u);   // lanes >=16: don't-care
      float pi = __shfl(rsum, s0,      64);
      float pf = __shfl(rsum, s0 + 8,  64);
      float pg = __shfl(rsum, s0 + 16, 64);
      float po = __shfl(rsum, s0 + 24, 64);
      const bool act = (t < 8) ? d1 : ((t < 16) ? d2 : false);
      if (act){
        if (t < 8){
          pi += xv*wx[0] + bias[0];
          pf += xv*wx[1] + bias[1];
          pg += xv*wx[2] + bias[2];
          po += xv*wx[3] + bias[3];
        } else {
          pi += bias[0]; pf += bias[1]; pg += bias[2]; po += bias[3];
        }
        cst  = sigf(pf)*cst + sigf(pi)*tanhf_fast(pg);
        hcur = sigf(po)*tanhf_fast(cst);
      }
      if (t < 16){
        u64 pr = ((u64)(g + 1u) << 32) | (u64)__builtin_bit_cast(unsigned, hcur);
        u64* nb = (u64*)(comm + ((g+1u) & 1u)*SLOTF + wg*LINEF);
        __hip_atomic_store(nb + t, pr, __ATOMIC_RELAXED, AS);
      }
    }
  };

  // o = Wlin . h2 + blin from hvec chunks 2/3; result in ALL wave-0 lanes
  auto computeO = [&](int oi, float& xv){
    if (rg == 0){
      float s = dot4(wl0, ((const float4*)(hvec + 2*STR))[t])
              + dot4(wl1, ((const float4*)(hvec + 3*STR))[t]);
      #pragma unroll
      for (int m=1;m<64;m<<=1) s += __shfl_xor(s, m, 64);
      xv = s + blin0;
      if (wg == 0 && t == 0) out[oi] = xv;
    }
  };

  __syncthreads();   // xrow staged

  unsigned g = 0;

  // ---- teacher: tick g computes L1 step g || L2 step g-1 ----
  for (int tk=0; tk<TT; ++tk, ++g){
    poll_stage(g);                       // hvec = [h1_{g-1} | h2_{g-2}]
    dots_reduce();
    __syncthreads();
    tail(g, true, tk >= 1, xrow[tk]);    // publish [h1_g | h2_{g-1}] pairs
  }

  // ---- drain: L2 step 1023 ----
  poll_stage(g);                         // [h1_1023 | h2_1022]
  dots_reduce();
  __syncthreads();
  tail(g, false, true, 0.f);             // publish [h1_1023 | h2_1023]
  ++g;

  // ---- AR: steps s = 1024..1086, 2 ticks each ----
  for (int s=TT; s<TT+PRED-1; ++s){
    poll_stage(g);                       // [h1_{s-1} | h2_{s-1}]
    float xv = 0.f;
    computeO(s - TT, xv);                // emit out[s-TT] (o_{s-1})
    dots_reduce();
    __syncthreads();
    tail(g, true, false, xv);            // publish [h1_s | h2_{s-1}]
    ++g;

    poll_stage(g);                       // [h1_s | h2_{s-1}]
    dots_reduce();
    __syncthreads();
    tail(g, false, true, 0.f);           // publish [h1_s | h2_s]
    ++g;
  }

  // ---- final output o_1086 ----
  poll_stage(g);                         // [h1_1086 | h2_1086]
  float xv;
  computeO(PRED - 1, xv);
}

extern "C" void kernel_launch(void* const* d_in, const int* in_sizes, int n_in,
                              void* d_out, int out_size, void* d_ws, size_t ws_size,
                              hipStream_t stream) {
  const float* input = (const float*)d_in[0];
  // d_in[1] = pred_len (fixed 64, baked in)
  const float* Wih1 = (const float*)d_in[2];
  const float* Whh1 = (const float*)d_in[3];
  const float* bih1 = (const float*)d_in[4];
  const float* bhh1 = (const float*)d_in[5];
  const float* Wih2 = (const float*)d_in[6];
  const float* Whh2 = (const float*)d_in[7];
  const float* bih2 = (const float*)d_in[8];
  const float* bhh2 = (const float*)d_in[9];
  const float* Wlin = (const float*)d_in[10];
  const float* blin = (const float*)d_in[11];

  // zero comm: u64 zero pairs == (gen 0, h=0.0f) -> valid initial state
  hipMemsetAsync(d_ws, 0, 2 * SLOTF * sizeof(float), stream);

  lstm2_kernel<<<dim3(G), dim3(NT), 0, stream>>>(
      input, Wih1, Whh1, bih1, bhh1, Wih2, Whh2, bih2, bhh2, Wlin, blin,
      (float*)d_out, (float*)d_ws);
}